// Round 12
// baseline (5405.092 us; speedup 1.0000x reference)
//
#include <hip/hip_runtime.h>
#include <hip/hip_bf16.h>

#define NPTS 8192
#define KS   1024
#define NB   16

// ===========================================================================
// FPS round-12: each batch split across 16 blocks x 256 threads (2 pts/thr,
// coords fully register-resident -- kills the rounds-4/6/11 reload/AGPR
// saga). Grid = 16 batches x 16 parts = 256 blocks = 1 per CU.
// Per step: local exact distance update (bit-exact jnp order, contract off),
// wave64 packed-u64 max butterfly, 4-wave LDS reduce, then a 16-block
// exchange through agent-scope atomic slots in d_ws. Packed u64 =
// [valbits:32][~idx:13][tag:19], tag = step+1 (ws poison 0xAA -> tag
// 0x2AAAA never aliases; same-step compare reduces to (val, lowest idx) --
// exact jnp.argmax first-occurrence tie-break). Winner index -> SGPR,
// centroid re-read from x. Deterministic result regardless of timing.
// Deadlock-safe: 65536 threads total, all blocks co-resident.
// ===========================================================================
__global__ __launch_bounds__(256, 1)
void fps_kernel(const float* __restrict__ x, int* __restrict__ idx_out,
                unsigned long long* __restrict__ slots) {
#pragma clang fp contract(off)
  const int blk  = blockIdx.x;
  const int b    = blk >> 4;
  const int part = blk & 15;
  const int tid  = threadIdx.x;
  const int lane = tid & 63;
  const int wave = tid >> 6;                 // 0..3
  const float* xb = x + (size_t)b * NPTS * 6;
  const int p0   = part * 512 + tid * 2;     // this thread's first point

  float crd[12];
  {
    const float4* src = reinterpret_cast<const float4*>(xb + (size_t)p0 * 6);
    #pragma unroll
    for (int i = 0; i < 3; ++i) {
      float4 v = src[i];
      crd[4*i+0] = v.x; crd[4*i+1] = v.y; crd[4*i+2] = v.z; crd[4*i+3] = v.w;
    }
  }
  float d0 = __builtin_huge_valf(), d1 = __builtin_huge_valf();

  unsigned long long* bsl = slots + b * 16;
  __shared__ unsigned long long ws4[4];
  __shared__ unsigned long long gws;

  if (part == 0 && tid == 0) idx_out[b * KS] = 0;
  int bi = 0;                                // uniform winner index

  for (int step = 0; step < KS - 1; ++step) {
    const float* cp = xb + bi * 6;           // uniform -> scalar loads
    const float c0 = cp[0], c1 = cp[1], c2 = cp[2],
                c3 = cp[3], c4 = cp[4], c5 = cp[5];

    float bestv; int besti;
    {
      float t0 = crd[0] - c0; float s = t0 * t0;
      float t1 = crd[1] - c1; s = s + t1 * t1;
      float t2 = crd[2] - c2; s = s + t2 * t2;
      float t3 = crd[3] - c3; s = s + t3 * t3;
      float t4 = crd[4] - c4; s = s + t4 * t4;
      float t5 = crd[5] - c5; s = s + t5 * t5;
      d0 = fminf(d0, s);
      bestv = d0; besti = p0;
    }
    {
      float t0 = crd[6]  - c0; float s = t0 * t0;
      float t1 = crd[7]  - c1; s = s + t1 * t1;
      float t2 = crd[8]  - c2; s = s + t2 * t2;
      float t3 = crd[9]  - c3; s = s + t3 * t3;
      float t4 = crd[10] - c4; s = s + t4 * t4;
      float t5 = crd[11] - c5; s = s + t5 * t5;
      d1 = fminf(d1, s);
      if (d1 > bestv) { bestv = d1; besti = p0 + 1; }   // ascending: lowest idx on tie
    }

    unsigned long long pk = ((unsigned long long)__float_as_uint(bestv) << 32)
                          | ((unsigned long long)((~besti) & 0x1FFF) << 19)
                          | (unsigned long long)(step + 1);
    // wave64 butterfly max
    #pragma unroll
    for (int off = 1; off < 64; off <<= 1) {
      unsigned long long o = __shfl_xor(pk, off, 64);
      if (o > pk) pk = o;
    }
    if (lane == 0) ws4[wave] = pk;
    __syncthreads();
    // block-level: every lane reduces the 4 wave slots (2 stages)
    unsigned long long bw = ws4[lane & 3];
    #pragma unroll
    for (int off = 1; off < 4; off <<= 1) {
      unsigned long long o = __shfl_xor(bw, off, 64);
      if (o > bw) bw = o;
    }
    // publish block winner
    if (tid == 0)
      __hip_atomic_store(&bsl[part], bw, __ATOMIC_RELEASE, __HIP_MEMORY_SCOPE_AGENT);
    // wave 0: gather all 16 block results (lanes 0-15, divergent spin)
    if (wave == 0) {
      unsigned long long r = 0;
      if (lane < 16) {
        if (lane == part) {
          r = bw;
        } else {
          do {
            r = __hip_atomic_load(&bsl[lane], __ATOMIC_ACQUIRE, __HIP_MEMORY_SCOPE_AGENT);
          } while ((unsigned)(r & 0x7FFFFull) != (unsigned)(step + 1));
        }
      }
      #pragma unroll
      for (int off = 1; off < 16; off <<= 1) {
        unsigned long long o = __shfl_xor(r, off, 64);
        if (o > r) r = o;
      }
      if (lane == 0) gws = r;
    }
    __syncthreads();
    const unsigned long long w = gws;
    bi = (int)__builtin_amdgcn_readfirstlane((unsigned)((~(w >> 19)) & 0x1FFF));
    if (part == 0 && tid == 0) idx_out[b * KS + step + 1] = bi;
  }
}

// ===========================================================================
// Sine-MLP on the 16384 sampled points only. 64 pts/block, 1024 threads
// (16 waves x 4 pts). Acts in LDS [p][c]; W tile transposed in LDS
// [c][COUT+1] (conflict-free). Unchanged from round 11 (passed, ~336us).
// ===========================================================================
template<int NT, int JP, int CINP, int CINT, int COUT, int CT, bool LAST>
__device__ __forceinline__ void run_layer(const float* __restrict__ W,
                                          const float* __restrict__ bias,
                                          const float* __restrict__ in,
                                          float* __restrict__ outlds,
                                          float* __restrict__ gout,
                                          float* __restrict__ wt,
                                          int qbase, int tid) {
  constexpr int S = (COUT + 63) / 64;
  const int lane = tid & 63;
  const int wave = tid >> 6;
  const int p0   = wave * JP;

  float acc[JP][S];
  {
    float bv[S];
    #pragma unroll
    for (int s = 0; s < S; ++s) {
      int o = s * 64 + lane;
      bv[s] = (o < COUT) ? bias[o] : 0.f;
    }
    #pragma unroll
    for (int j = 0; j < JP; ++j)
      #pragma unroll
      for (int s = 0; s < S; ++s) acc[j][s] = bv[s];
  }

  for (int ct0 = 0; ct0 < CINT; ct0 += CT) {
    __syncthreads();
    #pragma unroll 1
    for (int e = tid; e < COUT * CT; e += NT) {
      int o  = e / CT;           // CT compile-time
      int cc = e % CT;
      wt[cc * (COUT + 1) + o] = W[o * CINT + ct0 + cc];
    }
    __syncthreads();
    #pragma unroll
    for (int cc0 = 0; cc0 < CT; cc0 += 4) {
      if (CT - cc0 >= 4) {
        float a[JP][4];
        #pragma unroll
        for (int j = 0; j < JP; ++j) {
          float4 t = *reinterpret_cast<const float4*>(&in[(p0 + j) * CINP + ct0 + cc0]);
          a[j][0] = t.x; a[j][1] = t.y; a[j][2] = t.z; a[j][3] = t.w;
        }
        #pragma unroll
        for (int u = 0; u < 4; ++u) {
          float wvv[S];
          #pragma unroll
          for (int s = 0; s < S; ++s)
            wvv[s] = wt[(cc0 + u) * (COUT + 1) + s * 64 + lane];
          #pragma unroll
          for (int j = 0; j < JP; ++j)
            #pragma unroll
            for (int s = 0; s < S; ++s)
              acc[j][s] = fmaf(a[j][u], wvv[s], acc[j][s]);
        }
      } else {   // remainder of 2 (layer 1, CT=6)
        float a[JP][2];
        #pragma unroll
        for (int j = 0; j < JP; ++j) {
          float2 t = *reinterpret_cast<const float2*>(&in[(p0 + j) * CINP + ct0 + cc0]);
          a[j][0] = t.x; a[j][1] = t.y;
        }
        #pragma unroll
        for (int u = 0; u < 2; ++u) {
          float wvv[S];
          #pragma unroll
          for (int s = 0; s < S; ++s)
            wvv[s] = wt[(cc0 + u) * (COUT + 1) + s * 64 + lane];
          #pragma unroll
          for (int j = 0; j < JP; ++j)
            #pragma unroll
            for (int s = 0; s < S; ++s)
              acc[j][s] = fmaf(a[j][u], wvv[s], acc[j][s]);
        }
      }
    }
  }
  #pragma unroll
  for (int j = 0; j < JP; ++j) {
    #pragma unroll
    for (int s = 0; s < S; ++s) {
      int o = s * 64 + lane;
      if (o < COUT) {
        float r = sinf(acc[j][s]);
        if (LAST) gout[(size_t)(qbase + p0 + j) * 512 + o] = r;
        else      outlds[(p0 + j) * COUT + o] = r;
      }
    }
  }
}

__global__ __launch_bounds__(1024, 4) void mlp_kernel(
    const float* __restrict__ x, const int* __restrict__ sidx,
    const float* __restrict__ W1, const float* __restrict__ B1,
    const float* __restrict__ W2, const float* __restrict__ B2,
    const float* __restrict__ W3, const float* __restrict__ B3,
    const float* __restrict__ W4, const float* __restrict__ B4,
    const float* __restrict__ W5, const float* __restrict__ B5,
    const float* __restrict__ W6, const float* __restrict__ B6,
    float* __restrict__ out) {
  __shared__ float A[64 * 128];
  __shared__ float Bb[64 * 256];
  __shared__ float wt[16 * 513];
  const int tid   = threadIdx.x;
  const int qbase = blockIdx.x * 64;

  if (tid < 64) {              // gather sampled points, stride-8 rows
    int q  = qbase + tid;
    int bb = q >> 10;
    int id = sidx[q];
    const float* xr = x + ((size_t)bb * NPTS + id) * 6;
    #pragma unroll
    for (int d = 0; d < 6; ++d) A[tid * 8 + d] = xr[d];
  }
  // (first barrier inside run_layer covers the gather)
  run_layer<1024, 4, 8,   6,  32,  6, false>(W1, B1, A,  Bb, nullptr, wt, qbase, tid);
  run_layer<1024, 4, 32,  32,  64, 16, false>(W2, B2, Bb, A,  nullptr, wt, qbase, tid);
  run_layer<1024, 4, 64,  64,  64, 16, false>(W3, B3, A,  Bb, nullptr, wt, qbase, tid);
  run_layer<1024, 4, 64,  64, 128, 16, false>(W4, B4, Bb, A,  nullptr, wt, qbase, tid);
  run_layer<1024, 4, 128, 128, 256, 16, false>(W5, B5, A,  Bb, nullptr, wt, qbase, tid);
  run_layer<1024, 4, 256, 256, 512, 16, true >(W6, B6, Bb, nullptr, out, wt, qbase, tid);
}

extern "C" void kernel_launch(void* const* d_in, const int* in_sizes, int n_in,
                              void* d_out, int out_size, void* d_ws, size_t ws_size,
                              hipStream_t stream) {
  const float* x  = (const float*)d_in[0];
  const float* W1 = (const float*)d_in[1];  const float* B1 = (const float*)d_in[2];
  const float* W2 = (const float*)d_in[3];  const float* B2 = (const float*)d_in[4];
  const float* W3 = (const float*)d_in[5];  const float* B3 = (const float*)d_in[6];
  const float* W4 = (const float*)d_in[7];  const float* B4 = (const float*)d_in[8];
  const float* W5 = (const float*)d_in[9];  const float* B5 = (const float*)d_in[10];
  const float* W6 = (const float*)d_in[11]; const float* B6 = (const float*)d_in[12];

  unsigned long long* slots = (unsigned long long*)d_ws;   // 16*16*8 = 2 KB
  int* idxbuf = (int*)((char*)d_ws + 4096);                // 64 KB
  float* out  = (float*)d_out;                             // [16,1024,512] fp32

  fps_kernel<<<256, 256, 0, stream>>>(x, idxbuf, slots);
  mlp_kernel<<<256, 1024, 0, stream>>>(x, idxbuf,
                                       W1, B1, W2, B2, W3, B3,
                                       W4, B4, W5, B5, W6, B6, out);
}

// Round 13
// 1977.351 us; speedup vs baseline: 2.7335x; 2.7335x over previous
//
#include <hip/hip_runtime.h>
#include <hip/hip_bf16.h>

#define NPTS 8192
#define KS   1024
#define NB   16

// ===========================================================================
// FPS: one block per batch, 1024 threads, 8 pts/thread.
// Round-13: coords loaded via OPAQUE inline-asm global_load_dwordx4 -- the
// compiler cannot rematerialize asm outputs, so the 48 floats stay VGPR-
// resident (rounds 4/6: regalloc's remat heuristic kept VGPR=40 and
// re-streamed ~196KB/step from L1/L2, ~1000+ cyc/step; round 11's AGPR fix
// removed the stream but added 48 serial VALU reads -- net loss; round 12's
// multi-block exchange cost 7-9k cyc/step in cross-XCD atomics -- reverted).
// Distance math: bit-exact vs jnp (sequential sub/mul/add, fp contract OFF).
// NO fmaf / dot-product forms: estimated argmax flip probability over 16K
// selections is 1-10% -- permanently rejected.
// Reduce: value-only f32 max butterfly + ballot/ctz/readlane (first-
// occurrence tie-break: lane order == index order at both levels).
// ONE barrier/step; parity-double-buffered per-wave results; centroid via
// SGPR-uniform scalar load from x.
// ===========================================================================
__global__ __launch_bounds__(1024, 4)
__attribute__((amdgpu_waves_per_eu(4, 4)))
void fps_kernel(const float* __restrict__ x, int* __restrict__ idx_out) {
#pragma clang fp contract(off)
  const int b    = blockIdx.x;
  const int tid  = threadIdx.x;
  const int lane = tid & 63;
  const int wave = tid >> 6;
  const float* xb = x + (size_t)b * NPTS * 6;

  // Opaque loads: 12 float4 = this thread's 8 points (48 floats, 192 B).
  float4 qa[12];
  {
    unsigned long long a = (unsigned long long)(xb + (size_t)tid * 48);
    asm volatile("global_load_dwordx4 %0, %1, off offset:0"   : "=v"(qa[0])  : "v"(a));
    asm volatile("global_load_dwordx4 %0, %1, off offset:16"  : "=v"(qa[1])  : "v"(a));
    asm volatile("global_load_dwordx4 %0, %1, off offset:32"  : "=v"(qa[2])  : "v"(a));
    asm volatile("global_load_dwordx4 %0, %1, off offset:48"  : "=v"(qa[3])  : "v"(a));
    asm volatile("global_load_dwordx4 %0, %1, off offset:64"  : "=v"(qa[4])  : "v"(a));
    asm volatile("global_load_dwordx4 %0, %1, off offset:80"  : "=v"(qa[5])  : "v"(a));
    asm volatile("global_load_dwordx4 %0, %1, off offset:96"  : "=v"(qa[6])  : "v"(a));
    asm volatile("global_load_dwordx4 %0, %1, off offset:112" : "=v"(qa[7])  : "v"(a));
    asm volatile("global_load_dwordx4 %0, %1, off offset:128" : "=v"(qa[8])  : "v"(a));
    asm volatile("global_load_dwordx4 %0, %1, off offset:144" : "=v"(qa[9])  : "v"(a));
    asm volatile("global_load_dwordx4 %0, %1, off offset:160" : "=v"(qa[10]) : "v"(a));
    asm volatile("global_load_dwordx4 %0, %1, off offset:176" : "=v"(qa[11]) : "v"(a));
    asm volatile("s_waitcnt vmcnt(0)" ::: "memory");
  }
  float crd[48];
  #pragma unroll
  for (int i = 0; i < 12; ++i) {
    crd[4*i+0] = qa[i].x; crd[4*i+1] = qa[i].y;
    crd[4*i+2] = qa[i].z; crd[4*i+3] = qa[i].w;
  }

  float dist[8];
  #pragma unroll
  for (int j = 0; j < 8; ++j) dist[j] = __builtin_huge_valf();

  __shared__ uint2 wvi[2][16];     // [step parity][wave] = {idx, valbits}

  if (tid == 0) idx_out[b * KS] = 0;
  int bi = 0;                      // wave-uniform (SGPR) winner index

  for (int step = 0; step < KS - 1; ++step) {
    const float* cp = xb + bi * 6;             // uniform -> scalar loads
    const float c0 = cp[0], c1 = cp[1], c2 = cp[2],
                c3 = cp[3], c4 = cp[4], c5 = cp[5];

    float bestv = -1.0f;                       // all dists >= 0
    int   besti = 0;
    #pragma unroll
    for (int j = 0; j < 8; ++j) {
      // bit-exact jnp order: sequential non-contracted sum of squares
      float t0 = crd[6*j+0] - c0; float s = t0 * t0;
      float t1 = crd[6*j+1] - c1; s = s + t1 * t1;
      float t2 = crd[6*j+2] - c2; s = s + t2 * t2;
      float t3 = crd[6*j+3] - c3; s = s + t3 * t3;
      float t4 = crd[6*j+4] - c4; s = s + t4 * t4;
      float t5 = crd[6*j+5] - c5; s = s + t5 * t5;
      float nd = fminf(dist[j], s);
      dist[j] = nd;
      if (nd > bestv) { bestv = nd; besti = tid * 8 + j; }  // ascending j: lowest idx on tie
    }

    // wave64 value-only max butterfly (6 x (swizzle + v_max))
    float wmax = bestv;
    #pragma unroll
    for (int off = 1; off < 64; off <<= 1)
      wmax = fmaxf(wmax, __shfl_xor(wmax, off, 64));
    // index: lowest lane whose bestv equals the max == first occurrence
    unsigned long long ball = __ballot(bestv == wmax);
    int wlane = (int)__builtin_ctzll(ball);
    int widx  = __builtin_amdgcn_readlane(besti, wlane);

    if (lane == 0) wvi[step & 1][wave] = make_uint2((unsigned)widx, __float_as_uint(wmax));
    __syncthreads();

    // every wave reduces the 16 per-wave results (redundant; no 2nd barrier)
    uint2 wr = wvi[step & 1][lane & 15];
    float cv = __uint_as_float(wr.y);
    #pragma unroll
    for (int off = 1; off < 16; off <<= 1)
      cv = fmaxf(cv, __shfl_xor(cv, off, 64));
    unsigned long long b2 = __ballot(__uint_as_float(wr.y) == cv);
    int cl = (int)__builtin_ctzll(b2);         // lowest wave among ties
    bi = __builtin_amdgcn_readlane((int)wr.x, cl);

    if (tid == 0) idx_out[b * KS + step + 1] = bi;
  }
}

// ===========================================================================
// Sine-MLP on the 16384 sampled points only. 64 pts/block, 1024 threads
// (16 waves x 4 pts). Acts in LDS [p][c]; W tile transposed in LDS
// [c][COUT+1] (conflict-free). Unchanged from round 11 (passed, ~336us).
// ===========================================================================
template<int NT, int JP, int CINP, int CINT, int COUT, int CT, bool LAST>
__device__ __forceinline__ void run_layer(const float* __restrict__ W,
                                          const float* __restrict__ bias,
                                          const float* __restrict__ in,
                                          float* __restrict__ outlds,
                                          float* __restrict__ gout,
                                          float* __restrict__ wt,
                                          int qbase, int tid) {
  constexpr int S = (COUT + 63) / 64;
  const int lane = tid & 63;
  const int wave = tid >> 6;
  const int p0   = wave * JP;

  float acc[JP][S];
  {
    float bv[S];
    #pragma unroll
    for (int s = 0; s < S; ++s) {
      int o = s * 64 + lane;
      bv[s] = (o < COUT) ? bias[o] : 0.f;
    }
    #pragma unroll
    for (int j = 0; j < JP; ++j)
      #pragma unroll
      for (int s = 0; s < S; ++s) acc[j][s] = bv[s];
  }

  for (int ct0 = 0; ct0 < CINT; ct0 += CT) {
    __syncthreads();
    #pragma unroll 1
    for (int e = tid; e < COUT * CT; e += NT) {
      int o  = e / CT;           // CT compile-time
      int cc = e % CT;
      wt[cc * (COUT + 1) + o] = W[o * CINT + ct0 + cc];
    }
    __syncthreads();
    #pragma unroll
    for (int cc0 = 0; cc0 < CT; cc0 += 4) {
      if (CT - cc0 >= 4) {
        float a[JP][4];
        #pragma unroll
        for (int j = 0; j < JP; ++j) {
          float4 t = *reinterpret_cast<const float4*>(&in[(p0 + j) * CINP + ct0 + cc0]);
          a[j][0] = t.x; a[j][1] = t.y; a[j][2] = t.z; a[j][3] = t.w;
        }
        #pragma unroll
        for (int u = 0; u < 4; ++u) {
          float wvv[S];
          #pragma unroll
          for (int s = 0; s < S; ++s)
            wvv[s] = wt[(cc0 + u) * (COUT + 1) + s * 64 + lane];
          #pragma unroll
          for (int j = 0; j < JP; ++j)
            #pragma unroll
            for (int s = 0; s < S; ++s)
              acc[j][s] = fmaf(a[j][u], wvv[s], acc[j][s]);
        }
      } else {   // remainder of 2 (layer 1, CT=6)
        float a[JP][2];
        #pragma unroll
        for (int j = 0; j < JP; ++j) {
          float2 t = *reinterpret_cast<const float2*>(&in[(p0 + j) * CINP + ct0 + cc0]);
          a[j][0] = t.x; a[j][1] = t.y;
        }
        #pragma unroll
        for (int u = 0; u < 2; ++u) {
          float wvv[S];
          #pragma unroll
          for (int s = 0; s < S; ++s)
            wvv[s] = wt[(cc0 + u) * (COUT + 1) + s * 64 + lane];
          #pragma unroll
          for (int j = 0; j < JP; ++j)
            #pragma unroll
            for (int s = 0; s < S; ++s)
              acc[j][s] = fmaf(a[j][u], wvv[s], acc[j][s]);
        }
      }
    }
  }
  #pragma unroll
  for (int j = 0; j < JP; ++j) {
    #pragma unroll
    for (int s = 0; s < S; ++s) {
      int o = s * 64 + lane;
      if (o < COUT) {
        float r = sinf(acc[j][s]);
        if (LAST) gout[(size_t)(qbase + p0 + j) * 512 + o] = r;
        else      outlds[(p0 + j) * COUT + o] = r;
      }
    }
  }
}

__global__ __launch_bounds__(1024, 4) void mlp_kernel(
    const float* __restrict__ x, const int* __restrict__ sidx,
    const float* __restrict__ W1, const float* __restrict__ B1,
    const float* __restrict__ W2, const float* __restrict__ B2,
    const float* __restrict__ W3, const float* __restrict__ B3,
    const float* __restrict__ W4, const float* __restrict__ B4,
    const float* __restrict__ W5, const float* __restrict__ B5,
    const float* __restrict__ W6, const float* __restrict__ B6,
    float* __restrict__ out) {
  __shared__ float A[64 * 128];
  __shared__ float Bb[64 * 256];
  __shared__ float wt[16 * 513];
  const int tid   = threadIdx.x;
  const int qbase = blockIdx.x * 64;

  if (tid < 64) {              // gather sampled points, stride-8 rows
    int q  = qbase + tid;
    int bb = q >> 10;
    int id = sidx[q];
    const float* xr = x + ((size_t)bb * NPTS + id) * 6;
    #pragma unroll
    for (int d = 0; d < 6; ++d) A[tid * 8 + d] = xr[d];
  }
  // (first barrier inside run_layer covers the gather)
  run_layer<1024, 4, 8,   6,  32,  6, false>(W1, B1, A,  Bb, nullptr, wt, qbase, tid);
  run_layer<1024, 4, 32,  32,  64, 16, false>(W2, B2, Bb, A,  nullptr, wt, qbase, tid);
  run_layer<1024, 4, 64,  64,  64, 16, false>(W3, B3, A,  Bb, nullptr, wt, qbase, tid);
  run_layer<1024, 4, 64,  64, 128, 16, false>(W4, B4, Bb, A,  nullptr, wt, qbase, tid);
  run_layer<1024, 4, 128, 128, 256, 16, false>(W5, B5, A,  Bb, nullptr, wt, qbase, tid);
  run_layer<1024, 4, 256, 256, 512, 16, true >(W6, B6, Bb, nullptr, out, wt, qbase, tid);
}

extern "C" void kernel_launch(void* const* d_in, const int* in_sizes, int n_in,
                              void* d_out, int out_size, void* d_ws, size_t ws_size,
                              hipStream_t stream) {
  const float* x  = (const float*)d_in[0];
  const float* W1 = (const float*)d_in[1];  const float* B1 = (const float*)d_in[2];
  const float* W2 = (const float*)d_in[3];  const float* B2 = (const float*)d_in[4];
  const float* W3 = (const float*)d_in[5];  const float* B3 = (const float*)d_in[6];
  const float* W4 = (const float*)d_in[7];  const float* B4 = (const float*)d_in[8];
  const float* W5 = (const float*)d_in[9];  const float* B5 = (const float*)d_in[10];
  const float* W6 = (const float*)d_in[11]; const float* B6 = (const float*)d_in[12];
  int*   idxbuf = (int*)d_ws;                              // 64 KB scratch
  float* out    = (float*)d_out;                           // [16,1024,512] fp32

  fps_kernel<<<NB, 1024, 0, stream>>>(x, idxbuf);
  mlp_kernel<<<256, 1024, 0, stream>>>(x, idxbuf,
                                       W1, B1, W2, B2, W3, B3,
                                       W4, B4, W5, B5, W6, B6, out);
}